// Round 15
// baseline (135.847 us; speedup 1.0000x reference)
//
#include <hip/hip_runtime.h>
#include <hip/hip_bf16.h>

typedef float fvec4 __attribute__((ext_vector_type(4)));
typedef unsigned short ushort_t;
typedef unsigned int uint_t;

#define NBLK 512            // 2 blocks per CU
#define TPB  512
#define NG   8              // waves per block
#define CN   256            // nodes per chunk

// Defeat LICM: opaque pointer so the 4 type blocks' weight loads cannot be
// merged/hoisted into one 192-float live set (the R2-R6 spill disease).
#define LAUNDER_PTR(p) asm volatile("" : "+v"(p))

// ---- LDS layout ----
// floats: [XSH CN*16 = 4096][IDX 2x(4*CN) ushorts = 1024 floats][CNT 8 ints]
// then bf16 tables (ushort) from float offset 5128.
#define XSH    0                    // CN*16 floats (rows padded 14->16)
#define IDXF   4096                 // 2 buffers x 4*CN ushorts (=1024 floats)
#define CNTI   5120                 // 8 ints
#define TABF   5128                 // table base as float offset
#define TABU   (TABF * 2)           // = 10256 ushort offset

// table offsets (ushort units, relative to tab) — type-0 padded to stride 88,
// bases chosen so (base - first_col) % 4 == 0 => 8B-aligned uint2 gathers.
#define O_E0_2 0            // 96 x 88 = 8448
#define O_E0_3 8450         // 8  x 88 -> 9154   (8450-86  = 8364 %4==0)
#define O_E0_5 9155         // 2  x 88 -> 9331   (9155-171 = 8984 %4==0)
#define O_E1_2 9332         // 4  x 128
#define O_E1_3 9844         // 22 x 128          (9844-128 = 9716 %4==0)
#define O_E2_0 12660        // 6  x 256
#define O_E3_0 14196        // 15 x 128
#define O_E3_1 16116        // 96 x 128          (16116-128 = 15988 %4==0)
#define NTABU  28404
#define SMEM_BYTES (TABF * 4 + NTABU * 2)   // 20512 + 56808 = 77320 B (x2 = 154640 < 160 KiB/CU)

extern __shared__ float smem[];

__device__ __forceinline__ ushort_t f2bf(float v) {
    __hip_bfloat16 h = __float2bfloat16(v);
    return *reinterpret_cast<ushort_t*>(&h);
}
__device__ __forceinline__ float bf2f(ushort_t u) {
    return __uint_as_float(((uint_t)u) << 16);
}

#define FMA4(K, XV)                                   \
    acc.x = fmaf(w[0][K], (XV), acc.x);               \
    acc.y = fmaf(w[1][K], (XV), acc.y);               \
    acc.z = fmaf(w[2][K], (XV), acc.z);               \
    acc.w = fmaf(w[3][K], (XV), acc.w);

#define BF4_DECODE(u, ev)                             \
    ev.x = __uint_as_float(u.x << 16);                \
    ev.y = __uint_as_float(u.x & 0xffff0000u);        \
    ev.z = __uint_as_float(u.y << 16);                \
    ev.w = __uint_as_float(u.y & 0xffff0000u);

__global__ __launch_bounds__(TPB, 4)
void node_enc_kernel(const float* __restrict__ x,
                     const int* __restrict__ node_types,
                     const float* __restrict__ W0, const float* __restrict__ b0,
                     const float* __restrict__ E0_2, const float* __restrict__ E0_3,
                     const float* __restrict__ E0_5,
                     const float* __restrict__ W1, const float* __restrict__ b1,
                     const float* __restrict__ E1_2, const float* __restrict__ E1_3,
                     const float* __restrict__ W2, const float* __restrict__ b2,
                     const float* __restrict__ E2_0,
                     const float* __restrict__ W3, const float* __restrict__ b3,
                     const float* __restrict__ E3_0, const float* __restrict__ E3_1,
                     float* __restrict__ out, int n_nodes)
{
    const int tid = threadIdx.x;
    const int q   = tid & 63;    // lane: owns output cols 4q..4q+3
    const int h   = tid >> 6;    // wave index within block (0..7)

    ushort_t* const tab = reinterpret_cast<ushort_t*>(smem) + TABU;

    // ---------- copy embedding tables into LDS as bf16 (once per block) ----------
    auto copy_tab_bf = [&](const float* __restrict__ src, int dst, int n) {
        for (int i = tid; i < n; i += TPB) tab[dst + i] = f2bf(src[i]);
    };
    auto copy_tab_pad_bf = [&](const float* __restrict__ src, int dst, int rows, int cols) {
        const int n = rows * cols;
        for (int i = tid; i < n; i += TPB) {
            const int r = i / cols, c2 = i - r * cols;
            tab[dst + r * 88 + c2] = f2bf(src[i]);
        }
    };
    copy_tab_pad_bf(E0_2, O_E0_2, 96, 86);
    copy_tab_pad_bf(E0_3, O_E0_3, 8, 85);
    copy_tab_pad_bf(E0_5, O_E0_5, 2, 85);
    copy_tab_bf(E1_2, O_E1_2, 512);
    copy_tab_bf(E1_3, O_E1_3, 2816);
    copy_tab_bf(E2_0, O_E2_0, 1536);
    copy_tab_bf(E3_0, O_E3_0, 1920);
    copy_tab_bf(E3_1, O_E3_1, 12288);

    // ---------- chunk range for this block ----------
    const int nch = (n_nodes + CN - 1) / CN;
    const int c0  = (int)(((long long)blockIdx.x * nch) / NBLK);
    const int c1  = (int)(((long long)(blockIdx.x + 1) * nch) / NBLK);

    ushort_t* const idx_m = reinterpret_cast<ushort_t*>(&smem[IDXF]);  // 2 x 1024
    int*      const cnt_m = reinterpret_cast<int*>(&smem[CNTI]);       // 2 x 4
    const ushort_t* idx_ro = idx_m;
    const int*      cnt_ro = cnt_m;

    // ---------- staging helpers (reg-staged, issue-early / write-late) ----------
    auto stage_issue = [&](int c, fvec4& r0, fvec4& r1,
                           float& rs, int& ty, int& nv, int& total, int& cnn) {
        const long long cb = (long long)c * CN;
        cnn   = min(CN, (int)(n_nodes - cb));
        total = cnn * 14;
        nv    = total >> 2;            // max 896 (< 2*TPB)
        const fvec4* vsrc = reinterpret_cast<const fvec4*>(x + cb * 14);
        if (tid < nv)          r0 = __builtin_nontemporal_load(vsrc + tid);
        if (tid + TPB < nv)    r1 = __builtin_nontemporal_load(vsrc + tid + TPB);
        const int sf = (nv << 2) + tid;
        if (sf < total) rs = x[cb * 14 + sf];
        if (tid < cnn)  ty = node_types[cb + tid];
    };
    auto stage_write = [&](const fvec4& r0, const fvec4& r1,
                           float rs, int nv, int total) {
        auto wr1 = [&](int i, const fvec4& v) {
            const int f = i << 2;
            int node = f / 14, col = f - node * 14;
            #pragma unroll
            for (int j = 0; j < 4; ++j) {
                smem[XSH + node * 16 + col] = v[j];
                if (++col == 14) { col = 0; ++node; }
            }
        };
        if (tid < nv)        wr1(tid, r0);
        if (tid + TPB < nv)  wr1(tid + TPB, r1);
        const int sf = (nv << 2) + tid;
        if (sf < total) { const int node = sf / 14, col = sf - node * 14; smem[XSH + node * 16 + col] = rs; }
    };

    // ---------- compute one chunk (bucket buffer parity p) ----------
    auto do_chunk = [&](int c, int p) {
        const long long cb = (long long)c * CN;
        const int cbase = p * 4;        // counter base
        const int ibase = p * 1024;     // index-list base (ushorts)

        // ===== type 0 =====
        {
            const int m = cnt_ro[cbase + 0];
            const float* Wp = W0; LAUNDER_PTR(Wp);
            const float* bp = b0; LAUNDER_PTR(bp);
            float w[4][11];
            #pragma unroll
            for (int j = 0; j < 4; ++j) {
                #pragma unroll
                for (int k = 0; k < 11; ++k) w[j][k] = Wp[(4 * q + j) * 11 + k];
            }
            float4 bias;
            bias.x = bp[4 * q]; bias.y = bp[4 * q + 1];
            bias.z = bp[4 * q + 2]; bias.w = bp[4 * q + 3];
            int scv, ebase;
            const bool fb = (q == 21) || (q == 42);
            if (q <= 21)      { scv = 2; ebase = O_E0_2 + 4 * q; }
            else if (q <= 42) { scv = 3; ebase = (O_E0_3 - 86) + 4 * q; }
            else              { scv = 5; ebase = (O_E0_5 - 171) + 4 * q; }
            for (int g = h; g < m; g += NG) {
                const int nl = idx_ro[ibase + 0 * CN + g];
                const float* xr = &smem[XSH + nl * 16];
                const float4 ra = *reinterpret_cast<const float4*>(xr);
                const float4 rb = *reinterpret_cast<const float4*>(xr + 4);
                const float4 rc = *reinterpret_cast<const float4*>(xr + 8);
                const float2 rd = *reinterpret_cast<const float2*>(xr + 12);
                float4 acc = bias;
                FMA4(0,  ra.x) FMA4(1,  ra.y) FMA4(2,  rb.x) FMA4(3,  rb.z)
                FMA4(4,  rb.w) FMA4(5,  rc.x) FMA4(6,  rc.y) FMA4(7,  rc.z)
                FMA4(8,  rc.w) FMA4(9,  rd.x) FMA4(10, rd.y)
                float4 ev;
                if (fb) {
                    if (q == 21) {
                        const int c2 = (int)xr[2], c3 = (int)xr[3];
                        ev.x = bf2f(tab[O_E0_2 + c2 * 88 + 84]);
                        ev.y = bf2f(tab[O_E0_2 + c2 * 88 + 85]);
                        ev.z = bf2f(tab[O_E0_3 + c3 * 88 + 0]);
                        ev.w = bf2f(tab[O_E0_3 + c3 * 88 + 1]);
                    } else {
                        const int c3 = (int)xr[3], c5 = (int)xr[5];
                        ev.x = bf2f(tab[O_E0_3 + c3 * 88 + 82]);
                        ev.y = bf2f(tab[O_E0_3 + c3 * 88 + 83]);
                        ev.z = bf2f(tab[O_E0_3 + c3 * 88 + 84]);
                        ev.w = bf2f(tab[O_E0_5 + c5 * 88 + 0]);
                    }
                } else {
                    const int code = (int)xr[scv];
                    const uint2 u = *reinterpret_cast<const uint2*>(&tab[ebase + code * 88]);
                    BF4_DECODE(u, ev)
                }
                acc.x += ev.x; acc.y += ev.y; acc.z += ev.z; acc.w += ev.w;
                *reinterpret_cast<float4*>(&out[(cb + nl) * 256 + 4 * q]) = acc;
            }
        }

        // ===== type 1 =====
        {
            const int m = cnt_ro[cbase + 1];
            const float* Wp = W1; LAUNDER_PTR(Wp);
            const float* bp = b1; LAUNDER_PTR(bp);
            float w[4][12];
            #pragma unroll
            for (int j = 0; j < 4; ++j) {
                #pragma unroll
                for (int k = 0; k < 12; ++k) w[j][k] = Wp[(4 * q + j) * 12 + k];
            }
            float4 bias;
            bias.x = bp[4 * q]; bias.y = bp[4 * q + 1];
            bias.z = bp[4 * q + 2]; bias.w = bp[4 * q + 3];
            const int scv   = (q < 32) ? 2 : 3;
            const int ebase = ((q < 32) ? O_E1_2 : (O_E1_3 - 128)) + 4 * q;
            for (int g = h; g < m; g += NG) {
                const int nl = idx_ro[ibase + 1 * CN + g];
                const float* xr = &smem[XSH + nl * 16];
                const float4 ra = *reinterpret_cast<const float4*>(xr);
                const float4 rb = *reinterpret_cast<const float4*>(xr + 4);
                const float4 rc = *reinterpret_cast<const float4*>(xr + 8);
                const float2 rd = *reinterpret_cast<const float2*>(xr + 12);
                float4 acc = bias;
                FMA4(0,  ra.x) FMA4(1,  ra.y) FMA4(2,  rb.x) FMA4(3,  rb.y)
                FMA4(4,  rb.z) FMA4(5,  rb.w) FMA4(6,  rc.x) FMA4(7,  rc.y)
                FMA4(8,  rc.z) FMA4(9,  rc.w) FMA4(10, rd.x) FMA4(11, rd.y)
                const int code = (int)xr[scv];
                const uint2 u = *reinterpret_cast<const uint2*>(&tab[ebase + code * 128]);
                float4 ev;
                BF4_DECODE(u, ev)
                acc.x += ev.x; acc.y += ev.y; acc.z += ev.z; acc.w += ev.w;
                *reinterpret_cast<float4*>(&out[(cb + nl) * 256 + 4 * q]) = acc;
            }
        }

        // ===== type 2 =====
        {
            const int m = cnt_ro[cbase + 2];
            const float* Wp = W2; LAUNDER_PTR(Wp);
            const float* bp = b2; LAUNDER_PTR(bp);
            float w[4][12];
            #pragma unroll
            for (int j = 0; j < 4; ++j) {
                #pragma unroll
                for (int k = 0; k < 12; ++k) w[j][k] = Wp[(4 * q + j) * 12 + k];
            }
            float4 bias;
            bias.x = bp[4 * q]; bias.y = bp[4 * q + 1];
            bias.z = bp[4 * q + 2]; bias.w = bp[4 * q + 3];
            const int ebase = O_E2_0 + 4 * q;
            for (int g = h; g < m; g += NG) {
                const int nl = idx_ro[ibase + 2 * CN + g];
                const float* xr = &smem[XSH + nl * 16];
                const float4 ra = *reinterpret_cast<const float4*>(xr);
                const float4 rb = *reinterpret_cast<const float4*>(xr + 4);
                const float4 rc = *reinterpret_cast<const float4*>(xr + 8);
                const float2 rd = *reinterpret_cast<const float2*>(xr + 12);
                float4 acc = bias;
                FMA4(0,  ra.y) FMA4(1,  ra.z) FMA4(2,  rb.x) FMA4(3,  rb.y)
                FMA4(4,  rb.z) FMA4(5,  rb.w) FMA4(6,  rc.x) FMA4(7,  rc.y)
                FMA4(8,  rc.z) FMA4(9,  rc.w) FMA4(10, rd.x) FMA4(11, rd.y)
                const int code = (int)xr[0];
                const uint2 u = *reinterpret_cast<const uint2*>(&tab[ebase + code * 256]);
                float4 ev;
                BF4_DECODE(u, ev)
                acc.x += ev.x; acc.y += ev.y; acc.z += ev.z; acc.w += ev.w;
                *reinterpret_cast<float4*>(&out[(cb + nl) * 256 + 4 * q]) = acc;
            }
        }

        // ===== type 3 =====
        {
            const int m = cnt_ro[cbase + 3];
            const float* Wp = W3; LAUNDER_PTR(Wp);
            const float* bp = b3; LAUNDER_PTR(bp);
            float w[4][12];
            #pragma unroll
            for (int j = 0; j < 4; ++j) {
                #pragma unroll
                for (int k = 0; k < 12; ++k) w[j][k] = Wp[(4 * q + j) * 12 + k];
            }
            float4 bias;
            bias.x = bp[4 * q]; bias.y = bp[4 * q + 1];
            bias.z = bp[4 * q + 2]; bias.w = bp[4 * q + 3];
            const int scv   = (q < 32) ? 0 : 1;
            const int ebase = ((q < 32) ? O_E3_0 : (O_E3_1 - 128)) + 4 * q;
            for (int g = h; g < m; g += NG) {
                const int nl = idx_ro[ibase + 3 * CN + g];
                const float* xr = &smem[XSH + nl * 16];
                const float4 ra = *reinterpret_cast<const float4*>(xr);
                const float4 rb = *reinterpret_cast<const float4*>(xr + 4);
                const float4 rc = *reinterpret_cast<const float4*>(xr + 8);
                const float2 rd = *reinterpret_cast<const float2*>(xr + 12);
                float4 acc = bias;
                FMA4(0,  ra.z) FMA4(1,  ra.w) FMA4(2,  rb.x) FMA4(3,  rb.y)
                FMA4(4,  rb.z) FMA4(5,  rb.w) FMA4(6,  rc.x) FMA4(7,  rc.y)
                FMA4(8,  rc.z) FMA4(9,  rc.w) FMA4(10, rd.x) FMA4(11, rd.y)
                const int code = (int)xr[scv];
                const uint2 u = *reinterpret_cast<const uint2*>(&tab[ebase + code * 128]);
                float4 ev;
                BF4_DECODE(u, ev)
                acc.x += ev.x; acc.y += ev.y; acc.z += ev.z; acc.w += ev.w;
                *reinterpret_cast<float4*>(&out[(cb + nl) * 256 + 4 * q]) = acc;
            }
        }
    };

    // ---------- prologue: stage + bucket first chunk into buffer 0 ----------
    {
        fvec4 r0, r1; float rs = 0.f; int ty = 0, nv = 0, total = 0, cnn = 0;
        if (c0 < c1) {
            stage_issue(c0, r0, r1, rs, ty, nv, total, cnn);
            stage_write(r0, r1, rs, nv, total);
            if (tid < 8) cnt_m[tid] = 0;
        }
        __syncthreads();
        if (c0 < c1 && tid < cnn) {
            const int p0 = atomicAdd(&cnt_m[0 + ty], 1);
            idx_m[0 + ty * CN + p0] = (ushort_t)tid;
        }
        __syncthreads();
    }

    // ---------- main loop: 2 barriers per chunk ----------
    for (int c = c0; c < c1; ++c) {
        const int p = (c - c0) & 1;
        fvec4 r0, r1; float rs = 0.f; int ty = 0, nv = 0, total = 0, cnn = 0;
        const bool hasnext = (c + 1 < c1);
        if (hasnext) {
            stage_issue(c + 1, r0, r1, rs, ty, nv, total, cnn);
            if (tid < 4) cnt_m[(p ^ 1) * 4 + tid] = 0;   // other buffer: safe during compute(c)
        }
        do_chunk(c, p);
        __syncthreads();                    // xsh/idx reads done; cnt reset visible
        if (hasnext) {
            stage_write(r0, r1, rs, nv, total);
            if (tid < cnn) {
                const int pos = atomicAdd(&cnt_m[(p ^ 1) * 4 + ty], 1);
                idx_m[(p ^ 1) * 1024 + ty * CN + pos] = (ushort_t)tid;
            }
        }
        __syncthreads();                    // staged chunk + lists ready
    }
}

extern "C" void kernel_launch(void* const* d_in, const int* in_sizes, int n_in,
                              void* d_out, int out_size, void* d_ws, size_t ws_size,
                              hipStream_t stream) {
    // setup_inputs() dict order:
    //  0:x  1:node_types  2:W0 3:b0 4:E0_2 5:E0_3 6:E0_5
    //  7:W1 8:b1 9:E1_2 10:E1_3  11:W2 12:b2 13:E2_0  14:W3 15:b3 16:E3_0 17:E3_1
    const float* xp   = (const float*)d_in[0];
    const int*   ntp  = (const int*)d_in[1];
    const float* W0 = (const float*)d_in[2];
    const float* b0 = (const float*)d_in[3];
    const float* E0_2 = (const float*)d_in[4];
    const float* E0_3 = (const float*)d_in[5];
    const float* E0_5 = (const float*)d_in[6];
    const float* W1 = (const float*)d_in[7];
    const float* b1 = (const float*)d_in[8];
    const float* E1_2 = (const float*)d_in[9];
    const float* E1_3 = (const float*)d_in[10];
    const float* W2 = (const float*)d_in[11];
    const float* b2 = (const float*)d_in[12];
    const float* E2_0 = (const float*)d_in[13];
    const float* W3 = (const float*)d_in[14];
    const float* b3 = (const float*)d_in[15];
    const float* E3_0 = (const float*)d_in[16];
    const float* E3_1 = (const float*)d_in[17];
    float* outp = (float*)d_out;

    const int n_nodes = in_sizes[1];

    (void)hipFuncSetAttribute(reinterpret_cast<const void*>(node_enc_kernel),
                              hipFuncAttributeMaxDynamicSharedMemorySize, SMEM_BYTES);

    node_enc_kernel<<<NBLK, TPB, SMEM_BYTES, stream>>>(
        xp, ntp, W0, b0, E0_2, E0_3, E0_5, W1, b1, E1_2, E1_3,
        W2, b2, E2_0, W3, b3, E3_0, E3_1, outp, n_nodes);
}

// Round 16
// 126.601 us; speedup vs baseline: 1.0730x; 1.0730x over previous
//
#include <hip/hip_runtime.h>

typedef float fvec4 __attribute__((ext_vector_type(4)));
typedef unsigned short ushort_t;

#define NBLK 256
#define TPB  1024
#define NG   16             // waves per block (node-interleave groups)
#define CN   512            // nodes per chunk

// Defeat LICM: opaque pointer so the 4 type blocks' weight loads cannot be
// merged/hoisted into one 192-float live set (the R2-R6 spill disease).
#define LAUNDER_PTR(p) asm volatile("" : "+v"(p))

// ---- LDS layout (float offsets) ----
// Type-0 tables padded to row stride 88 floats, with base offsets chosen so
// (base - first_col) % 4 == 0  =>  base + code*88 + (4q - first_col) stays
// 16B-aligned for the vectorized gather.
#define O_E0_2 0            // 96 x 88 = 8448
#define O_E0_3 8450         // 8  x 88 -> 9154   (8450-86  = 8364 % 4 == 0)
#define O_E0_5 9155         // 2  x 88 -> 9331   (9155-171 = 8984 % 4 == 0)
#define O_E1_2 9332         // 4  x 128
#define O_E1_3 9844         // 22 x 128          (9844-128 = 9716 % 4 == 0)
#define O_E2_0 12660        // 6  x 256
#define O_E3_0 14196        // 15 x 128
#define O_E3_1 16116        // 96 x 128          (16116-128 = 15988 % 4 == 0)
#define NTAB   28404
#define XSH    NTAB                 // CN*16 floats (rows padded 14->16)
#define IDXF   (XSH + CN * 16)      // 2 buffers x 4*CN ushorts = 2048 floats
#define CNTI   (IDXF + 2048)        // 8 ints (2 buffers x 4 counters)
#define SMEM_FLOATS (CNTI + 8)      // 38660
#define SMEM_BYTES  (SMEM_FLOATS * 4)   // 154640 B < 160 KiB

extern __shared__ float smem[];

#define FMA4(K, XV)                                   \
    acc.x = fmaf(w[0][K], (XV), acc.x);               \
    acc.y = fmaf(w[1][K], (XV), acc.y);               \
    acc.z = fmaf(w[2][K], (XV), acc.z);               \
    acc.w = fmaf(w[3][K], (XV), acc.w);

__global__ __launch_bounds__(TPB, 1)
void node_enc_kernel(const float* __restrict__ x,
                     const int* __restrict__ node_types,
                     const float* __restrict__ W0, const float* __restrict__ b0,
                     const float* __restrict__ E0_2, const float* __restrict__ E0_3,
                     const float* __restrict__ E0_5,
                     const float* __restrict__ W1, const float* __restrict__ b1,
                     const float* __restrict__ E1_2, const float* __restrict__ E1_3,
                     const float* __restrict__ W2, const float* __restrict__ b2,
                     const float* __restrict__ E2_0,
                     const float* __restrict__ W3, const float* __restrict__ b3,
                     const float* __restrict__ E3_0, const float* __restrict__ E3_1,
                     float* __restrict__ out, int n_nodes)
{
    const int tid = threadIdx.x;
    const int q   = tid & 63;    // lane: owns output cols 4q..4q+3
    const int h   = tid >> 6;    // wave index within block (0..15)

    // ---------- copy embedding tables into LDS (once per block) ----------
    auto copy_tab = [&](const float* __restrict__ src, int dst, int n) {
        if ((((uintptr_t)src) & 15) == 0) {
            const int nv = n >> 2;
            for (int i = tid; i < nv; i += TPB) {
                const fvec4 v = *(reinterpret_cast<const fvec4*>(src) + i);
                *reinterpret_cast<fvec4*>(&smem[dst + (i << 2)]) = v;
            }
            for (int i = (nv << 2) + tid; i < n; i += TPB) smem[dst + i] = src[i];
        } else {
            for (int i = tid; i < n; i += TPB) smem[dst + i] = src[i];
        }
    };
    auto copy_tab_pad = [&](const float* __restrict__ src, int dst, int rows, int cols) {
        const int n = rows * cols;
        for (int i = tid; i < n; i += TPB) {
            const int r = i / cols, c2 = i - r * cols;
            smem[dst + r * 88 + c2] = src[i];
        }
    };
    copy_tab_pad(E0_2, O_E0_2, 96, 86);
    copy_tab_pad(E0_3, O_E0_3, 8, 85);
    copy_tab_pad(E0_5, O_E0_5, 2, 85);
    copy_tab(E1_2, O_E1_2, 512);
    copy_tab(E1_3, O_E1_3, 2816);
    copy_tab(E2_0, O_E2_0, 1536);
    copy_tab(E3_0, O_E3_0, 1920);
    copy_tab(E3_1, O_E3_1, 12288);

    // ---------- chunk range for this block ----------
    const int nch = (n_nodes + CN - 1) / CN;
    const int c0  = (int)(((long long)blockIdx.x * nch) / NBLK);
    const int c1  = (int)(((long long)(blockIdx.x + 1) * nch) / NBLK);

    ushort_t* const idx_m = reinterpret_cast<ushort_t*>(&smem[IDXF]);  // 2 x 2048
    int*      const cnt_m = reinterpret_cast<int*>(&smem[CNTI]);       // 2 x 4
    const ushort_t* idx_ro = idx_m;
    const int*      cnt_ro = cnt_m;

    // ---------- staging helpers (reg-staged, issue-early / write-late) ----------
    auto stage_issue = [&](int c, fvec4& r0, fvec4& r1,
                           float& rs, int& ty, int& nv, int& total, int& cnn) {
        const long long cb = (long long)c * CN;
        cnn   = min(CN, (int)(n_nodes - cb));
        total = cnn * 14;
        nv    = total >> 2;            // max 1792 (< 2*TPB)
        const fvec4* vsrc = reinterpret_cast<const fvec4*>(x + cb * 14);
        if (tid < nv)          r0 = __builtin_nontemporal_load(vsrc + tid);
        if (tid + TPB < nv)    r1 = __builtin_nontemporal_load(vsrc + tid + TPB);
        const int sf = (nv << 2) + tid;
        if (sf < total) rs = x[cb * 14 + sf];
        if (tid < cnn)  ty = node_types[cb + tid];
    };
    auto stage_write = [&](const fvec4& r0, const fvec4& r1,
                           float rs, int nv, int total) {
        auto wr1 = [&](int i, const fvec4& v) {
            const int f = i << 2;
            int node = f / 14, col = f - node * 14;
            #pragma unroll
            for (int j = 0; j < 4; ++j) {
                smem[XSH + node * 16 + col] = v[j];
                if (++col == 14) { col = 0; ++node; }
            }
        };
        if (tid < nv)        wr1(tid, r0);
        if (tid + TPB < nv)  wr1(tid + TPB, r1);
        const int sf = (nv << 2) + tid;
        if (sf < total) { const int node = sf / 14, col = sf - node * 14; smem[XSH + node * 16 + col] = rs; }
    };

    // ---------- compute one chunk (bucket buffer parity p) ----------
    auto do_chunk = [&](int c, int p) {
        const long long cb = (long long)c * CN;
        const int cbase = p * 4;        // counter base
        const int ibase = p * 2048;     // index-list base (ushorts)

        // ===== type 0 =====
        {
            const int m = cnt_ro[cbase + 0];
            const float* Wp = W0; LAUNDER_PTR(Wp);
            const float* bp = b0; LAUNDER_PTR(bp);
            float w[4][11];
            #pragma unroll
            for (int j = 0; j < 4; ++j) {
                #pragma unroll
                for (int k = 0; k < 11; ++k) w[j][k] = Wp[(4 * q + j) * 11 + k];
            }
            float4 bias;
            bias.x = bp[4 * q]; bias.y = bp[4 * q + 1];
            bias.z = bp[4 * q + 2]; bias.w = bp[4 * q + 3];
            int scv, ebase;
            const bool fb = (q == 21) || (q == 42);
            if (q <= 21)      { scv = 2; ebase = O_E0_2 + 4 * q; }
            else if (q <= 42) { scv = 3; ebase = (O_E0_3 - 86) + 4 * q; }
            else              { scv = 5; ebase = (O_E0_5 - 171) + 4 * q; }
            for (int g = h; g < m; g += NG) {
                const int nl = idx_ro[ibase + 0 * CN + g];
                const float* xr = &smem[XSH + nl * 16];
                const float4 ra = *reinterpret_cast<const float4*>(xr);
                const float4 rb = *reinterpret_cast<const float4*>(xr + 4);
                const float4 rc = *reinterpret_cast<const float4*>(xr + 8);
                const float2 rd = *reinterpret_cast<const float2*>(xr + 12);
                float4 acc = bias;
                FMA4(0,  ra.x) FMA4(1,  ra.y) FMA4(2,  rb.x) FMA4(3,  rb.z)
                FMA4(4,  rb.w) FMA4(5,  rc.x) FMA4(6,  rc.y) FMA4(7,  rc.z)
                FMA4(8,  rc.w) FMA4(9,  rd.x) FMA4(10, rd.y)
                float4 ev;
                if (fb) {
                    if (q == 21) {
                        const int c2 = (int)xr[2], c3 = (int)xr[3];
                        ev.x = smem[O_E0_2 + c2 * 88 + 84];
                        ev.y = smem[O_E0_2 + c2 * 88 + 85];
                        ev.z = smem[O_E0_3 + c3 * 88 + 0];
                        ev.w = smem[O_E0_3 + c3 * 88 + 1];
                    } else {
                        const int c3 = (int)xr[3], c5 = (int)xr[5];
                        ev.x = smem[O_E0_3 + c3 * 88 + 82];
                        ev.y = smem[O_E0_3 + c3 * 88 + 83];
                        ev.z = smem[O_E0_3 + c3 * 88 + 84];
                        ev.w = smem[O_E0_5 + c5 * 88 + 0];
                    }
                } else {
                    const int code = (int)xr[scv];
                    ev = *reinterpret_cast<const float4*>(&smem[ebase + code * 88]);
                }
                acc.x += ev.x; acc.y += ev.y; acc.z += ev.z; acc.w += ev.w;
                *reinterpret_cast<float4*>(&out[(cb + nl) * 256 + 4 * q]) = acc;
            }
        }

        // ===== type 1 =====
        {
            const int m = cnt_ro[cbase + 1];
            const float* Wp = W1; LAUNDER_PTR(Wp);
            const float* bp = b1; LAUNDER_PTR(bp);
            float w[4][12];
            #pragma unroll
            for (int j = 0; j < 4; ++j) {
                #pragma unroll
                for (int k = 0; k < 12; ++k) w[j][k] = Wp[(4 * q + j) * 12 + k];
            }
            float4 bias;
            bias.x = bp[4 * q]; bias.y = bp[4 * q + 1];
            bias.z = bp[4 * q + 2]; bias.w = bp[4 * q + 3];
            const int scv   = (q < 32) ? 2 : 3;
            const int ebase = ((q < 32) ? O_E1_2 : (O_E1_3 - 128)) + 4 * q;
            for (int g = h; g < m; g += NG) {
                const int nl = idx_ro[ibase + 1 * CN + g];
                const float* xr = &smem[XSH + nl * 16];
                const float4 ra = *reinterpret_cast<const float4*>(xr);
                const float4 rb = *reinterpret_cast<const float4*>(xr + 4);
                const float4 rc = *reinterpret_cast<const float4*>(xr + 8);
                const float2 rd = *reinterpret_cast<const float2*>(xr + 12);
                float4 acc = bias;
                FMA4(0,  ra.x) FMA4(1,  ra.y) FMA4(2,  rb.x) FMA4(3,  rb.y)
                FMA4(4,  rb.z) FMA4(5,  rb.w) FMA4(6,  rc.x) FMA4(7,  rc.y)
                FMA4(8,  rc.z) FMA4(9,  rc.w) FMA4(10, rd.x) FMA4(11, rd.y)
                const int code = (int)xr[scv];
                const float4 ev = *reinterpret_cast<const float4*>(&smem[ebase + code * 128]);
                acc.x += ev.x; acc.y += ev.y; acc.z += ev.z; acc.w += ev.w;
                *reinterpret_cast<float4*>(&out[(cb + nl) * 256 + 4 * q]) = acc;
            }
        }

        // ===== type 2 =====
        {
            const int m = cnt_ro[cbase + 2];
            const float* Wp = W2; LAUNDER_PTR(Wp);
            const float* bp = b2; LAUNDER_PTR(bp);
            float w[4][12];
            #pragma unroll
            for (int j = 0; j < 4; ++j) {
                #pragma unroll
                for (int k = 0; k < 12; ++k) w[j][k] = Wp[(4 * q + j) * 12 + k];
            }
            float4 bias;
            bias.x = bp[4 * q]; bias.y = bp[4 * q + 1];
            bias.z = bp[4 * q + 2]; bias.w = bp[4 * q + 3];
            const int ebase = O_E2_0 + 4 * q;
            for (int g = h; g < m; g += NG) {
                const int nl = idx_ro[ibase + 2 * CN + g];
                const float* xr = &smem[XSH + nl * 16];
                const float4 ra = *reinterpret_cast<const float4*>(xr);
                const float4 rb = *reinterpret_cast<const float4*>(xr + 4);
                const float4 rc = *reinterpret_cast<const float4*>(xr + 8);
                const float2 rd = *reinterpret_cast<const float2*>(xr + 12);
                float4 acc = bias;
                FMA4(0,  ra.y) FMA4(1,  ra.z) FMA4(2,  rb.x) FMA4(3,  rb.y)
                FMA4(4,  rb.z) FMA4(5,  rb.w) FMA4(6,  rc.x) FMA4(7,  rc.y)
                FMA4(8,  rc.z) FMA4(9,  rc.w) FMA4(10, rd.x) FMA4(11, rd.y)
                const int code = (int)xr[0];
                const float4 ev = *reinterpret_cast<const float4*>(&smem[ebase + code * 256]);
                acc.x += ev.x; acc.y += ev.y; acc.z += ev.z; acc.w += ev.w;
                *reinterpret_cast<float4*>(&out[(cb + nl) * 256 + 4 * q]) = acc;
            }
        }

        // ===== type 3 =====
        {
            const int m = cnt_ro[cbase + 3];
            const float* Wp = W3; LAUNDER_PTR(Wp);
            const float* bp = b3; LAUNDER_PTR(bp);
            float w[4][12];
            #pragma unroll
            for (int j = 0; j < 4; ++j) {
                #pragma unroll
                for (int k = 0; k < 12; ++k) w[j][k] = Wp[(4 * q + j) * 12 + k];
            }
            float4 bias;
            bias.x = bp[4 * q]; bias.y = bp[4 * q + 1];
            bias.z = bp[4 * q + 2]; bias.w = bp[4 * q + 3];
            const int scv   = (q < 32) ? 0 : 1;
            const int ebase = ((q < 32) ? O_E3_0 : (O_E3_1 - 128)) + 4 * q;
            for (int g = h; g < m; g += NG) {
                const int nl = idx_ro[ibase + 3 * CN + g];
                const float* xr = &smem[XSH + nl * 16];
                const float4 ra = *reinterpret_cast<const float4*>(xr);
                const float4 rb = *reinterpret_cast<const float4*>(xr + 4);
                const float4 rc = *reinterpret_cast<const float4*>(xr + 8);
                const float2 rd = *reinterpret_cast<const float2*>(xr + 12);
                float4 acc = bias;
                FMA4(0,  ra.z) FMA4(1,  ra.w) FMA4(2,  rb.x) FMA4(3,  rb.y)
                FMA4(4,  rb.z) FMA4(5,  rb.w) FMA4(6,  rc.x) FMA4(7,  rc.y)
                FMA4(8,  rc.z) FMA4(9,  rc.w) FMA4(10, rd.x) FMA4(11, rd.y)
                const int code = (int)xr[scv];
                const float4 ev = *reinterpret_cast<const float4*>(&smem[ebase + code * 128]);
                acc.x += ev.x; acc.y += ev.y; acc.z += ev.z; acc.w += ev.w;
                *reinterpret_cast<float4*>(&out[(cb + nl) * 256 + 4 * q]) = acc;
            }
        }
    };

    // ---------- prologue: stage + bucket first chunk into buffer 0 ----------
    {
        fvec4 r0, r1; float rs = 0.f; int ty = 0, nv = 0, total = 0, cnn = 0;
        if (c0 < c1) {
            stage_issue(c0, r0, r1, rs, ty, nv, total, cnn);
            stage_write(r0, r1, rs, nv, total);
            if (tid < 8) cnt_m[tid] = 0;
        }
        __syncthreads();
        if (c0 < c1 && tid < cnn) {
            const int p0 = atomicAdd(&cnt_m[0 + ty], 1);
            idx_m[0 + ty * CN + p0] = (ushort_t)tid;
        }
        __syncthreads();
    }

    // ---------- main loop: 2 barriers per chunk ----------
    // [reset cnt(p^1) || stage_issue(c+1) || compute(c, buf p)] -> bar ->
    // [stage_write(c+1) || bucket(c+1 -> buf p^1)] -> bar
    for (int c = c0; c < c1; ++c) {
        const int p = (c - c0) & 1;
        fvec4 r0, r1; float rs = 0.f; int ty = 0, nv = 0, total = 0, cnn = 0;
        const bool hasnext = (c + 1 < c1);
        if (hasnext) {
            stage_issue(c + 1, r0, r1, rs, ty, nv, total, cnn);
            if (tid < 4) cnt_m[(p ^ 1) * 4 + tid] = 0;   // other buffer: safe during compute(c)
        }
        do_chunk(c, p);
        __syncthreads();                    // xsh/idx reads done; cnt reset visible
        if (hasnext) {
            stage_write(r0, r1, rs, nv, total);
            if (tid < cnn) {
                const int pos = atomicAdd(&cnt_m[(p ^ 1) * 4 + ty], 1);
                idx_m[(p ^ 1) * 2048 + ty * CN + pos] = (ushort_t)tid;
            }
        }
        __syncthreads();                    // staged chunk + lists ready
    }
}

extern "C" void kernel_launch(void* const* d_in, const int* in_sizes, int n_in,
                              void* d_out, int out_size, void* d_ws, size_t ws_size,
                              hipStream_t stream) {
    // setup_inputs() dict order:
    //  0:x  1:node_types  2:W0 3:b0 4:E0_2 5:E0_3 6:E0_5
    //  7:W1 8:b1 9:E1_2 10:E1_3  11:W2 12:b2 13:E2_0  14:W3 15:b3 16:E3_0 17:E3_1
    const float* xp   = (const float*)d_in[0];
    const int*   ntp  = (const int*)d_in[1];
    const float* W0 = (const float*)d_in[2];
    const float* b0 = (const float*)d_in[3];
    const float* E0_2 = (const float*)d_in[4];
    const float* E0_3 = (const float*)d_in[5];
    const float* E0_5 = (const float*)d_in[6];
    const float* W1 = (const float*)d_in[7];
    const float* b1 = (const float*)d_in[8];
    const float* E1_2 = (const float*)d_in[9];
    const float* E1_3 = (const float*)d_in[10];
    const float* W2 = (const float*)d_in[11];
    const float* b2 = (const float*)d_in[12];
    const float* E2_0 = (const float*)d_in[13];
    const float* W3 = (const float*)d_in[14];
    const float* b3 = (const float*)d_in[15];
    const float* E3_0 = (const float*)d_in[16];
    const float* E3_1 = (const float*)d_in[17];
    float* outp = (float*)d_out;

    const int n_nodes = in_sizes[1];

    (void)hipFuncSetAttribute(reinterpret_cast<const void*>(node_enc_kernel),
                              hipFuncAttributeMaxDynamicSharedMemorySize, SMEM_BYTES);

    node_enc_kernel<<<NBLK, TPB, SMEM_BYTES, stream>>>(
        xp, ntp, W0, b0, E0_2, E0_3, E0_5, W1, b1, E1_2, E1_3,
        W2, b2, E2_0, W3, b3, E3_0, E3_1, outp, n_nodes);
}